// Round 5
// baseline (234.507 us; speedup 1.0000x reference)
//
#include <hip/hip_runtime.h>

#define TT 4096
#define DIN 1024

typedef _Float16 f16;
typedef __attribute__((ext_vector_type(8))) _Float16 f16x8;
typedef __attribute__((ext_vector_type(4))) _Float16 f16x4;
typedef __attribute__((ext_vector_type(4))) float f32x4;

// ---- device-global scratch ----
__device__ f16 g_xh[TT * DIN];               // x cast to f16            8 MB
__device__ f16 g_wqkvT[3 * DIN * DIN];       // [Wq^T|Wk^T|Wv^T] f16     6 MB
__device__ f16 g_wrT[DIN * DIN];             // Wr^T f16                 2 MB
__device__ f16 g_q[TT * DIN];                // q                        8 MB
__device__ f16 g_k[TT * DIN];                // k                        8 MB
__device__ f16 g_v[TT * DIN];                // v row-major              8 MB
__device__ f16 g_vT[DIN * TT];               // v transposed             8 MB
__device__ f16 g_sg[(size_t)TT * TT];        // gamma .* (q k^T)        32 MB
__device__ f16 g_part[4][TT * DIN];          // split-K partials f16    32 MB (reused by EPI2 then EPI3)
__device__ f16 g_ret[TT * DIN];              // retained                 8 MB

// ---- prep kernels ----
__global__ __launch_bounds__(256) void prep_cast_x(const float* __restrict__ x) {
    int i = (blockIdx.x * 256 + threadIdx.x) * 8;
    f32x4 a = *(const f32x4*)&x[i];
    f32x4 b = *(const f32x4*)&x[i + 4];
    f16x8 o;
#pragma unroll
    for (int j = 0; j < 4; ++j) { o[j] = (f16)a[j]; o[j + 4] = (f16)b[j]; }
    *(f16x8*)&g_xh[i] = o;
}

__global__ void prep_transpose(const float* __restrict__ Wq, const float* __restrict__ Wk,
                               const float* __restrict__ Wv, const float* __restrict__ Wr) {
    int idx = blockIdx.x * 256 + threadIdx.x;       // 0 .. 1M-1
    int which = blockIdx.y;                          // 0..3
    const float* src = (which == 0) ? Wq : (which == 1) ? Wk : (which == 2) ? Wv : Wr;
    f16* dst = (which < 3) ? (g_wqkvT + (size_t)which * DIN * DIN) : g_wrT;
    int j = idx >> 10, k = idx & 1023;
    dst[idx] = (f16)src[k * DIN + j];
}

// LDS-tiled transpose: g_v [4096][1024] -> g_vT [1024][4096]
__global__ __launch_bounds__(256) void transpose_v() {
    __shared__ f16 t[64][72];
    const int bc = blockIdx.x;
    const int br = blockIdx.y;
    const int tdx = threadIdx.x;
    const int r0 = tdx >> 3;
    const int c8 = (tdx & 7) * 8;
#pragma unroll
    for (int p = 0; p < 2; ++p) {
        int r = r0 + p * 32;
        *(f16x8*)&t[r][c8] = *(const f16x8*)&g_v[(size_t)(br * 64 + r) * DIN + bc * 64 + c8];
    }
    __syncthreads();
#pragma unroll
    for (int p = 0; p < 2; ++p) {
        int c = r0 + p * 32;
        f16x8 v;
#pragma unroll
        for (int j = 0; j < 8; ++j) v[j] = t[c8 + j][c];
        *(f16x8*)&g_vT[(size_t)(bc * 64 + c) * TT + br * 64 + c8] = v;
    }
}

// ---- async global->LDS, 16B per lane, wave-uniform LDS base ----
__device__ __forceinline__ void gload_lds16(const void* g, void* l) {
    __builtin_amdgcn_global_load_lds(
        (const __attribute__((address_space(1))) unsigned int*)g,
        (__attribute__((address_space(3))) unsigned int*)l,
        16, 0, 0);
}

// ================= 256x256 8-phase GEMM, C = A * B^T =================
// BK=64, 8 waves (2Mx4N), per-wave 128x64 out. LDS: 2 tile-buffers x 64KB.
// Swizzle: byte ^= (row&7)<<4 on stage SOURCE col and ds_read col.
//
// vmcnt ledger: steady kt outstanding = B(kt)4 + A(kt)4 + B(kt+1)4 = 12 ->
// vmcnt(4). Last kt: B(NT) never staged -> full drain vmcnt(0) (round-3 race fix).
//
// Epilogue (all EPIs): two-phase LDS repack. Row-half h: waves wr==h write acc
// f32 into LDS (XOR-swizzled), barrier, then ALL threads stream flat:
// contiguous b128 LDS reads -> per-EPI math -> packed coalesced stores.
//
// EPI 0: -> q|k|v f16 (+bias), select by blockIdx.x>>2
// EPI 1: -> g_sg = gamma .* C  (gamma as direct coalesced 1KB/wave row reads)
// EPI 2: -> g_part[z] f16, split-K over blockIdx.z (K=4096/4)
// EPI 3: -> g_part[z] f16, split-K over blockIdx.z (K=1024/4, NT=4)
template <int EPI>
__global__ __launch_bounds__(512, 2) void gemm8(const float* __restrict__ gamma,
                                                const float* __restrict__ bq,
                                                const float* __restrict__ bk,
                                                const float* __restrict__ bv,
                                                const float* __restrict__ br,
                                                const float* __restrict__ prelu_a,
                                                float* __restrict__ out) {
    constexpr int NT  = (EPI == 3) ? 4 : 16;         // K-tiles of 64
    constexpr int ld2A = (EPI == 2) ? 8192 : 2048;   // A row bytes
    constexpr int ld2B = (EPI == 2) ? 8192 : 2048;   // B row bytes

    const f16* Ap = (EPI == 0) ? g_xh : (EPI == 1) ? g_q : (EPI == 2) ? g_sg : g_ret;
    const f16* Bp = (EPI == 0) ? g_wqkvT : (EPI == 1) ? g_k : (EPI == 2) ? g_vT : g_wrT;
    const int kb_base = (EPI == 2) ? blockIdx.z * 2048
                      : (EPI == 3) ? blockIdx.z * 512 : 0;   // byte offset of K-slice

    __shared__ __align__(16) char smem[131072];

    const int t = threadIdx.x;
    const int w = t >> 6, l = t & 63;
    const int wr = w >> 2, wc = w & 3;               // 2M x 4N waves
    const int fr = l & 15;
    const int fkb = (l >> 4) * 16;                   // fragment k-byte (0..48)
    const int arow0 = blockIdx.y * 256;
    const int bcol0 = blockIdx.x * 256;

    auto stage = [&](const f16* M, int ld2, int row0, int kb0, int dstoff) {
#pragma unroll
        for (int r = 0; r < 2; ++r) {
            int off = r * 8192 + w * 1024;           // wave-uniform LDS offset
            int row = (off + l * 16) >> 7;
            int cb  = (l & 7) * 16;
            int scb = cb ^ ((row & 7) << 4);         // inverse-swizzle the SOURCE
            const char* src = (const char*)M + (size_t)(row0 + row) * ld2 + kb0 + scb;
            gload_lds16(src, smem + dstoff + off);
        }
    };

    auto ldsA = [&](int c, int m, int ks) -> f16x8 {
        int lr = m * 16 + fr;
        int kb = ks * 64 + fkb;
        return *(const f16x8*)(smem + c * 65536 + wr * 16384 + lr * 128 + (kb ^ ((lr & 7) << 4)));
    };
    auto ldsB = [&](int c, int n, int ks) -> f16x8 {
        int lc = (wc & 1) * 64 + n * 16 + fr;
        int kb = ks * 64 + fkb;
        return *(const f16x8*)(smem + c * 65536 + 32768 + (wc >> 1) * 16384 + lc * 128 + (kb ^ ((lc & 7) << 4)));
    };

#define KB(kt) (kb_base + (kt) * 128)

    // prologue: tile0 complete + tile1 B-halves (12 loads/thread in flight)
    stage(Ap, ld2A, arow0,       KB(0), 0);
    stage(Ap, ld2A, arow0 + 128, KB(0), 16384);
    stage(Bp, ld2B, bcol0,       KB(0), 32768);
    stage(Bp, ld2B, bcol0 + 128, KB(0), 49152);
    stage(Bp, ld2B, bcol0,       KB(1), 65536 + 32768);
    stage(Bp, ld2B, bcol0 + 128, KB(1), 65536 + 49152);

    f32x4 acc[8][4] = {};
    f16x8 bf[4][2];

#define GPHASE(MB, STAGE_STMT)                                              \
    {                                                                       \
        f16x8 af[2][2];                                                     \
        _Pragma("unroll") for (int i = 0; i < 2; ++i)                       \
            _Pragma("unroll") for (int ks = 0; ks < 2; ++ks)                \
                af[i][ks] = ldsA(c, (MB) + i, ks);                          \
        STAGE_STMT;                                                         \
        __builtin_amdgcn_s_barrier();                                       \
        __builtin_amdgcn_s_setprio(1);                                      \
        _Pragma("unroll") for (int i = 0; i < 2; ++i)                       \
            _Pragma("unroll") for (int n = 0; n < 4; ++n)                   \
                _Pragma("unroll") for (int ks = 0; ks < 2; ++ks)            \
                    acc[(MB) + i][n] = __builtin_amdgcn_mfma_f32_16x16x32_f16( \
                        af[i][ks], bf[n][ks], acc[(MB) + i][n], 0, 0, 0);   \
        __builtin_amdgcn_s_setprio(0);                                      \
        __builtin_amdgcn_s_barrier();                                       \
    }

    for (int kt = 0; kt < NT; ++kt) {
        const int c = kt & 1;
        if (kt == NT - 1) asm volatile("s_waitcnt vmcnt(0)" ::: "memory");
        else              asm volatile("s_waitcnt vmcnt(4)" ::: "memory");
        __builtin_amdgcn_s_barrier();
#pragma unroll
        for (int n = 0; n < 4; ++n)
#pragma unroll
            for (int ks = 0; ks < 2; ++ks) bf[n][ks] = ldsB(c, n, ks);
        GPHASE(0, if (kt + 1 < NT) stage(Ap, ld2A, arow0,       KB(kt + 1), (c ^ 1) * 65536))
        GPHASE(2, if (kt + 1 < NT) stage(Ap, ld2A, arow0 + 128, KB(kt + 1), (c ^ 1) * 65536 + 16384))
        GPHASE(4, if (kt + 2 < NT) stage(Bp, ld2B, bcol0,       KB(kt + 2), c * 65536 + 32768))
        GPHASE(6, if (kt + 2 < NT) stage(Bp, ld2B, bcol0 + 128, KB(kt + 2), c * 65536 + 49152))
    }
#undef GPHASE
#undef KB

    // ---------------- two-phase LDS-repack epilogue ----------------
    const int rb = (l >> 4) * 4;

    const int sel0 = (EPI == 0) ? (int)(blockIdx.x >> 2) : 0;   // 0=q 1=k 2=v
    f16* dst0 = nullptr;
    const float* bias0 = nullptr;
    if constexpr (EPI == 0) {
        dst0 = (sel0 == 0) ? g_q : (sel0 == 1) ? g_k : g_v;
        bias0 = (sel0 == 0) ? bq : (sel0 == 1) ? bk : bv;
    }
    f16* gp = nullptr;
    if constexpr (EPI == 2 || EPI == 3) gp = g_part[blockIdx.z];

    __syncthreads();                                 // K-loop LDS fully retired
#pragma unroll 1
    for (int h = 0; h < 2; ++h) {
        if (wr == h) {
            // write this wave's 128x256 f32 quarter... (its own rows) swizzled
#pragma unroll
            for (int m = 0; m < 8; ++m)
#pragma unroll
                for (int n = 0; n < 4; ++n)
#pragma unroll
                    for (int j = 0; j < 4; ++j) {
                        const int lr = m * 16 + rb + j;
                        const int cb = (wc * 64 + n * 16 + fr) * 4;
                        *(float*)(smem + lr * 1024 + (cb ^ ((lr & 7) << 4))) = acc[m][n][j];
                    }
        }
        __syncthreads();
        // flat streaming pass: 512 threads x 16 chunks of f32x4
#pragma unroll
        for (int it = 0; it < 16; ++it) {
            const int f  = t + it * 512;             // f32x4 chunk id 0..8191
            const int lr = f >> 6;                   // local row 0..127
            const int cb = (f & 63) * 16;            // byte col within row
            const f32x4 vv = *(const f32x4*)(smem + lr * 1024 + (cb ^ ((lr & 7) << 4)));
            const int row = arow0 + h * 128 + lr;
            const int c4  = cb >> 2;                 // element col 0..252
            if constexpr (EPI == 0) {
                const int colg = bcol0 - sel0 * 1024 + c4;
                const f32x4 b4 = *(const f32x4*)&bias0[colg];
                f16x4 o;
#pragma unroll
                for (int j = 0; j < 4; ++j) o[j] = (f16)(vv[j] + b4[j]);
                *(f16x4*)&dst0[(size_t)row * 1024 + colg] = o;
            } else if constexpr (EPI == 1) {
                const size_t gi = (size_t)row * TT + bcol0 + c4;
                const f32x4 g4 = *(const f32x4*)&gamma[gi];
                f16x4 o;
#pragma unroll
                for (int j = 0; j < 4; ++j) o[j] = (f16)(vv[j] * g4[j]);
                *(f16x4*)&g_sg[gi] = o;
            } else {
                f16x4 o;
#pragma unroll
                for (int j = 0; j < 4; ++j) o[j] = (f16)vv[j];
                *(f16x4*)&gp[(size_t)row * 1024 + bcol0 + c4] = o;
            }
        }
        __syncthreads();
    }
}

// sum 4 split-K f16 partials -> g_ret f16
__global__ __launch_bounds__(256) void reduce_parts() {
    size_t i = (size_t)(blockIdx.x * 256 + threadIdx.x) * 8;
    f16x8 a = *(const f16x8*)&g_part[0][i];
    f16x8 b = *(const f16x8*)&g_part[1][i];
    f16x8 cc = *(const f16x8*)&g_part[2][i];
    f16x8 d = *(const f16x8*)&g_part[3][i];
    f16x8 o;
#pragma unroll
    for (int j = 0; j < 8; ++j)
        o[j] = (f16)((float)a[j] + (float)b[j] + (float)cc[j] + (float)d[j]);
    *(f16x8*)&g_ret[i] = o;
}

// sum 4 split-K f16 partials + bias + PReLU -> out f32
__global__ __launch_bounds__(256) void reduce_out(const float* __restrict__ br,
                                                  const float* __restrict__ prelu_a,
                                                  float* __restrict__ out) {
    size_t i = (size_t)(blockIdx.x * 256 + threadIdx.x) * 8;
    f16x8 a = *(const f16x8*)&g_part[0][i];
    f16x8 b = *(const f16x8*)&g_part[1][i];
    f16x8 cc = *(const f16x8*)&g_part[2][i];
    f16x8 d = *(const f16x8*)&g_part[3][i];
    const float pa = *prelu_a;
    const int col = (int)(i & 1023);
    const f32x4 b0 = *(const f32x4*)&br[col];
    const f32x4 b1 = *(const f32x4*)&br[col + 4];
    f32x4 o0, o1;
#pragma unroll
    for (int j = 0; j < 4; ++j) {
        float s = (float)a[j] + (float)b[j] + (float)cc[j] + (float)d[j] + b0[j];
        o0[j] = (s >= 0.f) ? s : pa * s;
    }
#pragma unroll
    for (int j = 0; j < 4; ++j) {
        float s = (float)a[j + 4] + (float)b[j + 4] + (float)cc[j + 4] + (float)d[j + 4] + b1[j];
        o1[j] = (s >= 0.f) ? s : pa * s;
    }
    *(f32x4*)&out[i] = o0;
    *(f32x4*)&out[i + 4] = o1;
}

extern "C" void kernel_launch(void* const* d_in, const int* in_sizes, int n_in,
                              void* d_out, int out_size, void* d_ws, size_t ws_size,
                              hipStream_t stream) {
    const float* x     = (const float*)d_in[0];
    const float* gamma = (const float*)d_in[1];
    const float* Wq    = (const float*)d_in[2];
    const float* bq    = (const float*)d_in[3];
    const float* Wk    = (const float*)d_in[4];
    const float* bk    = (const float*)d_in[5];
    const float* Wv    = (const float*)d_in[6];
    const float* bv    = (const float*)d_in[7];
    const float* Wr    = (const float*)d_in[8];
    const float* br    = (const float*)d_in[9];
    const float* pa    = (const float*)d_in[10];
    float* out = (float*)d_out;

    prep_cast_x<<<TT * DIN / 8 / 256, 256, 0, stream>>>(x);
    prep_transpose<<<dim3(DIN * DIN / 256, 4), 256, 0, stream>>>(Wq, Wk, Wv, Wr);

    // EPI 0: qkv  M=4096 N=3072
    gemm8<0><<<dim3(12, 16), 512, 0, stream>>>(gamma, bq, bk, bv, br, pa, out);
    transpose_v<<<dim3(16, 64), 256, 0, stream>>>();
    // EPI 1: gamma .* (q k^T)  M=4096 N=4096
    gemm8<1><<<dim3(16, 16), 512, 0, stream>>>(gamma, bq, bk, bv, br, pa, out);
    // EPI 2: retained partials, split-K=4 over K=4096
    gemm8<2><<<dim3(4, 16, 4), 512, 0, stream>>>(gamma, bq, bk, bv, br, pa, out);
    reduce_parts<<<TT * DIN / 8 / 256, 256, 0, stream>>>();
    // EPI 3: out partials, split-K=4 over K=1024 (NT=4)
    gemm8<3><<<dim3(4, 16, 4), 512, 0, stream>>>(gamma, bq, bk, bv, br, pa, out);
    reduce_out<<<TT * DIN / 8 / 256, 256, 0, stream>>>(br, pa, out);
}

// Round 6
// 231.071 us; speedup vs baseline: 1.0149x; 1.0149x over previous
//
#include <hip/hip_runtime.h>

#define TT 4096
#define DIN 1024

typedef _Float16 f16;
typedef __attribute__((ext_vector_type(8))) _Float16 f16x8;
typedef __attribute__((ext_vector_type(4))) _Float16 f16x4;
typedef __attribute__((ext_vector_type(4))) float f32x4;

// ---- device-global scratch ----
__device__ f16 g_xh[TT * DIN];               // x cast to f16            8 MB
__device__ f16 g_wqkvT[3 * DIN * DIN];       // [Wq^T|Wk^T|Wv^T] f16     6 MB
__device__ f16 g_wrT[DIN * DIN];             // Wr^T f16                 2 MB
__device__ f16 g_q[TT * DIN];                // q                        8 MB
__device__ f16 g_k[TT * DIN];                // k                        8 MB
__device__ f16 g_v[TT * DIN];                // v row-major              8 MB
__device__ f16 g_vT[DIN * TT];               // v transposed             8 MB
__device__ f16 g_sg[(size_t)TT * TT];        // gamma .* (q k^T)        32 MB
__device__ f16 g_part[4][TT * DIN];          // split-K partials f16    32 MB
__device__ f16 g_ret[TT * DIN];              // retained                 8 MB

// ---- prep kernels ----
__global__ __launch_bounds__(256) void prep_cast_x(const float* __restrict__ x) {
    int i = (blockIdx.x * 256 + threadIdx.x) * 8;
    f32x4 a = *(const f32x4*)&x[i];
    f32x4 b = *(const f32x4*)&x[i + 4];
    f16x8 o;
#pragma unroll
    for (int j = 0; j < 4; ++j) { o[j] = (f16)a[j]; o[j + 4] = (f16)b[j]; }
    *(f16x8*)&g_xh[i] = o;
}

__global__ void prep_transpose(const float* __restrict__ Wq, const float* __restrict__ Wk,
                               const float* __restrict__ Wv, const float* __restrict__ Wr) {
    int idx = blockIdx.x * 256 + threadIdx.x;       // 0 .. 1M-1
    int which = blockIdx.y;                          // 0..3
    const float* src = (which == 0) ? Wq : (which == 1) ? Wk : (which == 2) ? Wv : Wr;
    f16* dst = (which < 3) ? (g_wqkvT + (size_t)which * DIN * DIN) : g_wrT;
    int j = idx >> 10, k = idx & 1023;
    dst[idx] = (f16)src[k * DIN + j];
}

// LDS-tiled transpose: g_v [4096][1024] -> g_vT [1024][4096]
__global__ __launch_bounds__(256) void transpose_v() {
    __shared__ f16 t[64][72];
    const int bc = blockIdx.x;
    const int br = blockIdx.y;
    const int tdx = threadIdx.x;
    const int r0 = tdx >> 3;
    const int c8 = (tdx & 7) * 8;
#pragma unroll
    for (int p = 0; p < 2; ++p) {
        int r = r0 + p * 32;
        *(f16x8*)&t[r][c8] = *(const f16x8*)&g_v[(size_t)(br * 64 + r) * DIN + bc * 64 + c8];
    }
    __syncthreads();
#pragma unroll
    for (int p = 0; p < 2; ++p) {
        int c = r0 + p * 32;
        f16x8 v;
#pragma unroll
        for (int j = 0; j < 8; ++j) v[j] = t[c8 + j][c];
        *(f16x8*)&g_vT[(size_t)(bc * 64 + c) * TT + br * 64 + c8] = v;
    }
}

// ---- async global->LDS, 16B per lane, wave-uniform LDS base ----
__device__ __forceinline__ void gload_lds16(const void* g, void* l) {
    __builtin_amdgcn_global_load_lds(
        (const __attribute__((address_space(1))) unsigned int*)g,
        (__attribute__((address_space(3))) unsigned int*)l,
        16, 0, 0);
}

// ================= 256x256 8-phase GEMM, C = A * B^T =================
// BK=64, 8 waves (2Mx4N), per-wave 128x64 out. LDS: 2 tile-buffers x 64KB
// (=> 1 block/CU; the 8-phase counted-vmcnt pipeline is the latency hider).
// Swizzle: byte ^= (row&7)<<4 on stage SOURCE col and ds_read col.
//
// vmcnt ledger: steady kt outstanding = B(kt)4 + A(kt)4 + B(kt+1)4 = 12 ->
// vmcnt(4). Last kt: B(NT) never staged -> full drain vmcnt(0) (race fix, r3).
//
// EPI 0: -> q|k|v f16 (+bias), select by blockIdx.x>>2; direct scalar stores
// EPI 1: -> g_sg = gamma .* C. gamma staged per 128-row half via async
//         global_load_lds burst (8192 outstanding 16B reqs/block — saturates
//         HBM at 1 block/CU, unlike scalar per-wave loads), LDS source-XOR
//         swizzled, then owner waves multiply+store direct.
// EPI 2: -> g_part[z] f16, split-K over blockIdx.z (K=4096/4)
// EPI 3: -> g_part[z] f16, split-K over blockIdx.z (K=1024/4, NT=4)
template <int EPI>
__global__ __launch_bounds__(512, 2) void gemm8(const float* __restrict__ gamma,
                                                const float* __restrict__ bq,
                                                const float* __restrict__ bk,
                                                const float* __restrict__ bv,
                                                const float* __restrict__ br,
                                                const float* __restrict__ prelu_a,
                                                float* __restrict__ out) {
    constexpr int NT  = (EPI == 3) ? 4 : 16;         // K-tiles of 64
    constexpr int ld2A = (EPI == 2) ? 8192 : 2048;   // A row bytes
    constexpr int ld2B = (EPI == 2) ? 8192 : 2048;   // B row bytes

    const f16* Ap = (EPI == 0) ? g_xh : (EPI == 1) ? g_q : (EPI == 2) ? g_sg : g_ret;
    const f16* Bp = (EPI == 0) ? g_wqkvT : (EPI == 1) ? g_k : (EPI == 2) ? g_vT : g_wrT;
    const int kb_base = (EPI == 2) ? blockIdx.z * 2048
                      : (EPI == 3) ? blockIdx.z * 512 : 0;   // byte offset of K-slice

    __shared__ __align__(16) char smem[131072];

    const int t = threadIdx.x;
    const int w = t >> 6, l = t & 63;
    const int wr = w >> 2, wc = w & 3;               // 2M x 4N waves
    const int fr = l & 15;
    const int fkb = (l >> 4) * 16;                   // fragment k-byte (0..48)
    const int arow0 = blockIdx.y * 256;
    const int bcol0 = blockIdx.x * 256;

    auto stage = [&](const f16* M, int ld2, int row0, int kb0, int dstoff) {
#pragma unroll
        for (int r = 0; r < 2; ++r) {
            int off = r * 8192 + w * 1024;           // wave-uniform LDS offset
            int row = (off + l * 16) >> 7;
            int cb  = (l & 7) * 16;
            int scb = cb ^ ((row & 7) << 4);         // inverse-swizzle the SOURCE
            const char* src = (const char*)M + (size_t)(row0 + row) * ld2 + kb0 + scb;
            gload_lds16(src, smem + dstoff + off);
        }
    };

    auto ldsA = [&](int c, int m, int ks) -> f16x8 {
        int lr = m * 16 + fr;
        int kb = ks * 64 + fkb;
        return *(const f16x8*)(smem + c * 65536 + wr * 16384 + lr * 128 + (kb ^ ((lr & 7) << 4)));
    };
    auto ldsB = [&](int c, int n, int ks) -> f16x8 {
        int lc = (wc & 1) * 64 + n * 16 + fr;
        int kb = ks * 64 + fkb;
        return *(const f16x8*)(smem + c * 65536 + 32768 + (wc >> 1) * 16384 + lc * 128 + (kb ^ ((lc & 7) << 4)));
    };

#define KB(kt) (kb_base + (kt) * 128)

    // prologue: tile0 complete + tile1 B-halves (12 loads/thread in flight)
    stage(Ap, ld2A, arow0,       KB(0), 0);
    stage(Ap, ld2A, arow0 + 128, KB(0), 16384);
    stage(Bp, ld2B, bcol0,       KB(0), 32768);
    stage(Bp, ld2B, bcol0 + 128, KB(0), 49152);
    stage(Bp, ld2B, bcol0,       KB(1), 65536 + 32768);
    stage(Bp, ld2B, bcol0 + 128, KB(1), 65536 + 49152);

    f32x4 acc[8][4] = {};
    f16x8 bf[4][2];

#define GPHASE(MB, STAGE_STMT)                                              \
    {                                                                       \
        f16x8 af[2][2];                                                     \
        _Pragma("unroll") for (int i = 0; i < 2; ++i)                       \
            _Pragma("unroll") for (int ks = 0; ks < 2; ++ks)                \
                af[i][ks] = ldsA(c, (MB) + i, ks);                          \
        STAGE_STMT;                                                         \
        __builtin_amdgcn_s_barrier();                                       \
        __builtin_amdgcn_s_setprio(1);                                      \
        _Pragma("unroll") for (int i = 0; i < 2; ++i)                       \
            _Pragma("unroll") for (int n = 0; n < 4; ++n)                   \
                _Pragma("unroll") for (int ks = 0; ks < 2; ++ks)            \
                    acc[(MB) + i][n] = __builtin_amdgcn_mfma_f32_16x16x32_f16( \
                        af[i][ks], bf[n][ks], acc[(MB) + i][n], 0, 0, 0);   \
        __builtin_amdgcn_s_setprio(0);                                      \
        __builtin_amdgcn_s_barrier();                                       \
    }

    for (int kt = 0; kt < NT; ++kt) {
        const int c = kt & 1;
        if (kt == NT - 1) asm volatile("s_waitcnt vmcnt(0)" ::: "memory");
        else              asm volatile("s_waitcnt vmcnt(4)" ::: "memory");
        __builtin_amdgcn_s_barrier();
#pragma unroll
        for (int n = 0; n < 4; ++n)
#pragma unroll
            for (int ks = 0; ks < 2; ++ks) bf[n][ks] = ldsB(c, n, ks);
        GPHASE(0, if (kt + 1 < NT) stage(Ap, ld2A, arow0,       KB(kt + 1), (c ^ 1) * 65536))
        GPHASE(2, if (kt + 1 < NT) stage(Ap, ld2A, arow0 + 128, KB(kt + 1), (c ^ 1) * 65536 + 16384))
        GPHASE(4, if (kt + 2 < NT) stage(Bp, ld2B, bcol0,       KB(kt + 2), c * 65536 + 32768))
        GPHASE(6, if (kt + 2 < NT) stage(Bp, ld2B, bcol0 + 128, KB(kt + 2), c * 65536 + 49152))
    }
#undef GPHASE
#undef KB

    // ---------------- epilogues ----------------
    const int rb = (l >> 4) * 4;
    const int crow0 = arow0 + wr * 128;
    const int ccol0 = bcol0 + wc * 64;

    if constexpr (EPI == 0) {
        const int sel = blockIdx.x >> 2;             // 0=q 1=k 2=v
        f16* dst = (sel == 0) ? g_q : (sel == 1) ? g_k : g_v;
        const float* bias = (sel == 0) ? bq : (sel == 1) ? bk : bv;
        const int cb0 = ccol0 - sel * 1024;
#pragma unroll
        for (int m = 0; m < 8; ++m)
#pragma unroll
            for (int n = 0; n < 4; ++n) {
                const int cl = cb0 + n * 16 + fr;
                const float bsum = bias[cl];
#pragma unroll
                for (int j = 0; j < 4; ++j)
                    dst[(size_t)(crow0 + m * 16 + rb + j) * 1024 + cl] = (f16)(acc[m][n][j] + bsum);
            }
    } else if constexpr (EPI == 1) {
        __syncthreads();                             // K-loop LDS retired, vmcnt==0
#pragma unroll 1
        for (int h = 0; h < 2; ++h) {
            // async burst: gamma rows [arow0+h*128,+128) x cols [bcol0,+256)
            // f32 -> 128KB LDS. Wave w stages row rr*8+w (1KB, 64x16B lanes).
            // Source col-byte XOR'd by (row&7)<<4 so LDS-linear holds the
            // swizzled layout (both-sides-or-neither).
#pragma unroll
            for (int rr = 0; rr < 16; ++rr) {
                const int row = rr * 8 + w;
                const int cbyte = (l * 16) ^ ((row & 7) << 4);
                const char* src = (const char*)(gamma + (size_t)(arow0 + h * 128 + row) * TT + bcol0) + cbyte;
                gload_lds16(src, smem + row * 1024);
            }
            asm volatile("s_waitcnt vmcnt(0)" ::: "memory");
            __syncthreads();
            if (wr == h) {
#pragma unroll
                for (int m = 0; m < 8; ++m)
#pragma unroll
                    for (int n = 0; n < 4; ++n) {
                        const int lcol = wc * 64 + n * 16 + fr;
#pragma unroll
                        for (int j = 0; j < 4; ++j) {
                            const int lrow = m * 16 + rb + j;
                            const float g = *(const float*)(smem + lrow * 1024 + ((lcol * 4) ^ ((lrow & 7) << 4)));
                            g_sg[(size_t)(arow0 + h * 128 + lrow) * TT + bcol0 + lcol] = (f16)(acc[m][n][j] * g);
                        }
                    }
            }
            __syncthreads();                         // readers done before h=1 overwrites
        }
    } else {
        f16* gp = g_part[blockIdx.z];
#pragma unroll
        for (int m = 0; m < 8; ++m)
#pragma unroll
            for (int n = 0; n < 4; ++n) {
                const int cl = ccol0 + n * 16 + fr;
#pragma unroll
                for (int j = 0; j < 4; ++j)
                    gp[(size_t)(crow0 + m * 16 + rb + j) * 1024 + cl] = (f16)acc[m][n][j];
            }
    }
}

// sum 4 split-K f16 partials -> g_ret f16
__global__ __launch_bounds__(256) void reduce_parts() {
    size_t i = (size_t)(blockIdx.x * 256 + threadIdx.x) * 8;
    f16x8 a = *(const f16x8*)&g_part[0][i];
    f16x8 b = *(const f16x8*)&g_part[1][i];
    f16x8 cc = *(const f16x8*)&g_part[2][i];
    f16x8 d = *(const f16x8*)&g_part[3][i];
    f16x8 o;
#pragma unroll
    for (int j = 0; j < 8; ++j)
        o[j] = (f16)((float)a[j] + (float)b[j] + (float)cc[j] + (float)d[j]);
    *(f16x8*)&g_ret[i] = o;
}

// sum 4 split-K f16 partials + bias + PReLU -> out f32
__global__ __launch_bounds__(256) void reduce_out(const float* __restrict__ br,
                                                  const float* __restrict__ prelu_a,
                                                  float* __restrict__ out) {
    size_t i = (size_t)(blockIdx.x * 256 + threadIdx.x) * 8;
    f16x8 a = *(const f16x8*)&g_part[0][i];
    f16x8 b = *(const f16x8*)&g_part[1][i];
    f16x8 cc = *(const f16x8*)&g_part[2][i];
    f16x8 d = *(const f16x8*)&g_part[3][i];
    const float pa = *prelu_a;
    const int col = (int)(i & 1023);
    const f32x4 b0 = *(const f32x4*)&br[col];
    const f32x4 b1 = *(const f32x4*)&br[col + 4];
    f32x4 o0, o1;
#pragma unroll
    for (int j = 0; j < 4; ++j) {
        float s = (float)a[j] + (float)b[j] + (float)cc[j] + (float)d[j] + b0[j];
        o0[j] = (s >= 0.f) ? s : pa * s;
    }
#pragma unroll
    for (int j = 0; j < 4; ++j) {
        float s = (float)a[j + 4] + (float)b[j + 4] + (float)cc[j + 4] + (float)d[j + 4] + b1[j];
        o1[j] = (s >= 0.f) ? s : pa * s;
    }
    *(f32x4*)&out[i] = o0;
    *(f32x4*)&out[i + 4] = o1;
}

extern "C" void kernel_launch(void* const* d_in, const int* in_sizes, int n_in,
                              void* d_out, int out_size, void* d_ws, size_t ws_size,
                              hipStream_t stream) {
    const float* x     = (const float*)d_in[0];
    const float* gamma = (const float*)d_in[1];
    const float* Wq    = (const float*)d_in[2];
    const float* bq    = (const float*)d_in[3];
    const float* Wk    = (const float*)d_in[4];
    const float* bk    = (const float*)d_in[5];
    const float* Wv    = (const float*)d_in[6];
    const float* bv    = (const float*)d_in[7];
    const float* Wr    = (const float*)d_in[8];
    const float* br    = (const float*)d_in[9];
    const float* pa    = (const float*)d_in[10];
    float* out = (float*)d_out;

    prep_cast_x<<<TT * DIN / 8 / 256, 256, 0, stream>>>(x);
    prep_transpose<<<dim3(DIN * DIN / 256, 4), 256, 0, stream>>>(Wq, Wk, Wv, Wr);

    // EPI 0: qkv  M=4096 N=3072
    gemm8<0><<<dim3(12, 16), 512, 0, stream>>>(gamma, bq, bk, bv, br, pa, out);
    transpose_v<<<dim3(16, 64), 256, 0, stream>>>();
    // EPI 1: gamma .* (q k^T)  M=4096 N=4096
    gemm8<1><<<dim3(16, 16), 512, 0, stream>>>(gamma, bq, bk, bv, br, pa, out);
    // EPI 2: retained partials, split-K=4 over K=4096
    gemm8<2><<<dim3(4, 16, 4), 512, 0, stream>>>(gamma, bq, bk, bv, br, pa, out);
    reduce_parts<<<TT * DIN / 8 / 256, 256, 0, stream>>>();
    // EPI 3: out partials, split-K=4 over K=1024 (NT=4)
    gemm8<3><<<dim3(4, 16, 4), 512, 0, stream>>>(gamma, bq, bk, bv, br, pa, out);
    reduce_out<<<TT * DIN / 8 / 256, 256, 0, stream>>>(br, pa, out);
}

// Round 7
// 200.484 us; speedup vs baseline: 1.1697x; 1.1526x over previous
//
#include <hip/hip_runtime.h>

#define TT 4096
#define DIN 1024

typedef _Float16 f16;
typedef __attribute__((ext_vector_type(8))) _Float16 f16x8;
typedef __attribute__((ext_vector_type(4))) _Float16 f16x4;
typedef __attribute__((ext_vector_type(4))) float f32x4;

// ---- device-global scratch ----
__device__ f16 g_xh[TT * DIN];               // x cast to f16            8 MB
__device__ f16 g_wqkvT[3 * DIN * DIN];       // [Wq^T|Wk^T|Wv^T] f16     6 MB
__device__ f16 g_wrT[DIN * DIN];             // Wr^T f16                 2 MB
__device__ f16 g_q[TT * DIN];                // q                        8 MB
__device__ f16 g_k[TT * DIN];                // k                        8 MB
__device__ f16 g_v[TT * DIN];                // v row-major              8 MB
__device__ f16 g_vT[DIN * TT];               // v transposed             8 MB
__device__ f16 g_sg[(size_t)TT * TT];        // S, then gamma.*S        32 MB
__device__ f16 g_part[4][TT * DIN];          // split-K partials f16    32 MB
__device__ f16 g_ret[TT * DIN];              // retained                 8 MB

// ---- prep kernels ----
__global__ __launch_bounds__(256) void prep_cast_x(const float* __restrict__ x) {
    int i = (blockIdx.x * 256 + threadIdx.x) * 8;
    f32x4 a = *(const f32x4*)&x[i];
    f32x4 b = *(const f32x4*)&x[i + 4];
    f16x8 o;
#pragma unroll
    for (int j = 0; j < 4; ++j) { o[j] = (f16)a[j]; o[j + 4] = (f16)b[j]; }
    *(f16x8*)&g_xh[i] = o;
}

__global__ void prep_transpose(const float* __restrict__ Wq, const float* __restrict__ Wk,
                               const float* __restrict__ Wv, const float* __restrict__ Wr) {
    int idx = blockIdx.x * 256 + threadIdx.x;       // 0 .. 1M-1
    int which = blockIdx.y;                          // 0..3
    const float* src = (which == 0) ? Wq : (which == 1) ? Wk : (which == 2) ? Wv : Wr;
    f16* dst = (which < 3) ? (g_wqkvT + (size_t)which * DIN * DIN) : g_wrT;
    int j = idx >> 10, k = idx & 1023;
    dst[idx] = (f16)src[k * DIN + j];
}

// LDS-tiled transpose: g_v [4096][1024] -> g_vT [1024][4096]
__global__ __launch_bounds__(256) void transpose_v() {
    __shared__ f16 t[64][72];
    const int bc = blockIdx.x;
    const int br = blockIdx.y;
    const int tdx = threadIdx.x;
    const int r0 = tdx >> 3;
    const int c8 = (tdx & 7) * 8;
#pragma unroll
    for (int p = 0; p < 2; ++p) {
        int r = r0 + p * 32;
        *(f16x8*)&t[r][c8] = *(const f16x8*)&g_v[(size_t)(br * 64 + r) * DIN + bc * 64 + c8];
    }
    __syncthreads();
#pragma unroll
    for (int p = 0; p < 2; ++p) {
        int c = r0 + p * 32;
        f16x8 v;
#pragma unroll
        for (int j = 0; j < 8; ++j) v[j] = t[c8 + j][c];
        *(f16x8*)&g_vT[(size_t)(bc * 64 + c) * TT + br * 64 + c8] = v;
    }
}

// streaming elementwise: g_sg = (f16)(g_sg * gamma), in-place, high occupancy
__global__ __launch_bounds__(256) void gamma_mult(const float* __restrict__ gamma) {
    const size_t total = (size_t)TT * TT;
    const size_t stride = (size_t)gridDim.x * 256 * 8;
    for (size_t i = ((size_t)blockIdx.x * 256 + threadIdx.x) * 8; i < total; i += stride) {
        f16x8 sv = *(const f16x8*)&g_sg[i];
        f32x4 g0 = *(const f32x4*)&gamma[i];
        f32x4 g1 = *(const f32x4*)&gamma[i + 4];
        f16x8 o;
#pragma unroll
        for (int j = 0; j < 4; ++j) {
            o[j]     = (f16)((float)sv[j] * g0[j]);
            o[j + 4] = (f16)((float)sv[j + 4] * g1[j]);
        }
        *(f16x8*)&g_sg[i] = o;
    }
}

// ---- async global->LDS, 16B per lane, wave-uniform LDS base ----
__device__ __forceinline__ void gload_lds16(const void* g, void* l) {
    __builtin_amdgcn_global_load_lds(
        (const __attribute__((address_space(1))) unsigned int*)g,
        (__attribute__((address_space(3))) unsigned int*)l,
        16, 0, 0);
}

// ================= 256x256 8-phase GEMM, C = A * B^T =================
// BK=64, 8 waves (2Mx4N), per-wave 128x64 out. LDS: 2 tile-buffers x 64KB.
// Swizzle: byte ^= (row&7)<<4 on stage SOURCE col and ds_read col.
// vmcnt ledger: steady kt outstanding = B(kt)4 + A(kt)4 + B(kt+1)4 = 12 ->
// vmcnt(4). Last kt: full drain vmcnt(0) (race fix, r3).
// T1: bijective XCD-chunked swizzle of (bx,by) — all grids have nwg%8==0.
//
// Epilogue (all EPIs): per-wave LDS micro-repack -> packed f16x8 stores.
// Wave-private 16KB slice (f16[128][64], XOR-swizzled): acc scalar-write,
// lgkmcnt(0) (wave-internal only), then 16x ds_read_b128 + 16B global
// stores (8x128B full-line segments per inst; kills partial-line RMW).
//
// EPI 0: -> q|k|v f16 (+bias), select by bx>>2
// EPI 1: -> g_sg = S  (pure GEMM; gamma applied by gamma_mult)
// EPI 2: -> g_part[z] f16, split-K over blockIdx.z (K=4096/4)
// EPI 3: -> g_part[z] f16, split-K over blockIdx.z (K=1024/4, NT=4)
template <int EPI>
__global__ __launch_bounds__(512, 2) void gemm8(const float* __restrict__ bq,
                                                const float* __restrict__ bk,
                                                const float* __restrict__ bv) {
    constexpr int NT  = (EPI == 3) ? 4 : 16;         // K-tiles of 64
    constexpr int ld2A = (EPI == 2) ? 8192 : 2048;   // A row bytes
    constexpr int ld2B = (EPI == 2) ? 8192 : 2048;   // B row bytes

    const f16* Ap = (EPI == 0) ? g_xh : (EPI == 1) ? g_q : (EPI == 2) ? g_sg : g_ret;
    const f16* Bp = (EPI == 0) ? g_wqkvT : (EPI == 1) ? g_k : (EPI == 2) ? g_vT : g_wrT;
    const int kb_base = (EPI == 2) ? blockIdx.z * 2048
                      : (EPI == 3) ? blockIdx.z * 512 : 0;   // byte offset of K-slice

    __shared__ __align__(16) char smem[131072];

    const int t = threadIdx.x;
    const int w = t >> 6, l = t & 63;
    const int wr = w >> 2, wc = w & 3;               // 2M x 4N waves
    const int fr = l & 15;
    const int fkb = (l >> 4) * 16;                   // fragment k-byte (0..48)

    // T1 bijective XCD swizzle over (x,y)
    const int nx = gridDim.x;
    const int lin = blockIdx.y * nx + blockIdx.x;
    const int cpx = (nx * gridDim.y) >> 3;
    const int sw = (lin & 7) * cpx + (lin >> 3);
    const int bx = sw % nx, by = sw / nx;
    const int arow0 = by * 256;
    const int bcol0 = bx * 256;

    auto stage = [&](const f16* M, int ld2, int row0, int kb0, int dstoff) {
#pragma unroll
        for (int r = 0; r < 2; ++r) {
            int off = r * 8192 + w * 1024;           // wave-uniform LDS offset
            int row = (off + l * 16) >> 7;
            int cb  = (l & 7) * 16;
            int scb = cb ^ ((row & 7) << 4);         // inverse-swizzle the SOURCE
            const char* src = (const char*)M + (size_t)(row0 + row) * ld2 + kb0 + scb;
            gload_lds16(src, smem + dstoff + off);
        }
    };

    auto ldsA = [&](int c, int m, int ks) -> f16x8 {
        int lr = m * 16 + fr;
        int kb = ks * 64 + fkb;
        return *(const f16x8*)(smem + c * 65536 + wr * 16384 + lr * 128 + (kb ^ ((lr & 7) << 4)));
    };
    auto ldsB = [&](int c, int n, int ks) -> f16x8 {
        int lc = (wc & 1) * 64 + n * 16 + fr;
        int kb = ks * 64 + fkb;
        return *(const f16x8*)(smem + c * 65536 + 32768 + (wc >> 1) * 16384 + lc * 128 + (kb ^ ((lc & 7) << 4)));
    };

#define KB(kt) (kb_base + (kt) * 128)

    // prologue: tile0 complete + tile1 B-halves (12 loads/thread in flight)
    stage(Ap, ld2A, arow0,       KB(0), 0);
    stage(Ap, ld2A, arow0 + 128, KB(0), 16384);
    stage(Bp, ld2B, bcol0,       KB(0), 32768);
    stage(Bp, ld2B, bcol0 + 128, KB(0), 49152);
    stage(Bp, ld2B, bcol0,       KB(1), 65536 + 32768);
    stage(Bp, ld2B, bcol0 + 128, KB(1), 65536 + 49152);

    f32x4 acc[8][4] = {};
    f16x8 bf[4][2];

#define GPHASE(MB, STAGE_STMT)                                              \
    {                                                                       \
        f16x8 af[2][2];                                                     \
        _Pragma("unroll") for (int i = 0; i < 2; ++i)                       \
            _Pragma("unroll") for (int ks = 0; ks < 2; ++ks)                \
                af[i][ks] = ldsA(c, (MB) + i, ks);                          \
        STAGE_STMT;                                                         \
        __builtin_amdgcn_s_barrier();                                       \
        __builtin_amdgcn_s_setprio(1);                                      \
        _Pragma("unroll") for (int i = 0; i < 2; ++i)                       \
            _Pragma("unroll") for (int n = 0; n < 4; ++n)                   \
                _Pragma("unroll") for (int ks = 0; ks < 2; ++ks)            \
                    acc[(MB) + i][n] = __builtin_amdgcn_mfma_f32_16x16x32_f16( \
                        af[i][ks], bf[n][ks], acc[(MB) + i][n], 0, 0, 0);   \
        __builtin_amdgcn_s_setprio(0);                                      \
        __builtin_amdgcn_s_barrier();                                       \
    }

    for (int kt = 0; kt < NT; ++kt) {
        const int c = kt & 1;
        if (kt == NT - 1) asm volatile("s_waitcnt vmcnt(0)" ::: "memory");
        else              asm volatile("s_waitcnt vmcnt(4)" ::: "memory");
        __builtin_amdgcn_s_barrier();
#pragma unroll
        for (int n = 0; n < 4; ++n)
#pragma unroll
            for (int ks = 0; ks < 2; ++ks) bf[n][ks] = ldsB(c, n, ks);
        GPHASE(0, if (kt + 1 < NT) stage(Ap, ld2A, arow0,       KB(kt + 1), (c ^ 1) * 65536))
        GPHASE(2, if (kt + 1 < NT) stage(Ap, ld2A, arow0 + 128, KB(kt + 1), (c ^ 1) * 65536 + 16384))
        GPHASE(4, if (kt + 2 < NT) stage(Bp, ld2B, bcol0,       KB(kt + 2), c * 65536 + 32768))
        GPHASE(6, if (kt + 2 < NT) stage(Bp, ld2B, bcol0 + 128, KB(kt + 2), c * 65536 + 49152))
    }
#undef GPHASE
#undef KB

    // ------------- per-wave LDS micro-repack epilogue -------------
    __syncthreads();                                 // K-loop LDS fully retired
    char* slice = smem + w * 16384;                  // wave-private f16[128][64]
    const int rb = (l >> 4) * 4;
    const int crow0 = arow0 + wr * 128;
    const int ccol0 = bcol0 + wc * 64;

    const int sel = (EPI == 0) ? (bx >> 2) : 0;      // 0=q 1=k 2=v
    const float* bias0 = (EPI == 0) ? ((sel == 0) ? bq : (sel == 1) ? bk : bv) : nullptr;
    const int cb0 = (EPI == 0) ? (ccol0 - sel * 1024) : ccol0;

    // phase 1: acc (+bias) -> f16 into swizzled wave slice
#pragma unroll
    for (int m = 0; m < 8; ++m)
#pragma unroll
        for (int n = 0; n < 4; ++n) {
            float bsum = 0.f;
            if constexpr (EPI == 0) bsum = bias0[cb0 + n * 16 + fr];
#pragma unroll
            for (int j = 0; j < 4; ++j) {
                const int lr = m * 16 + rb + j;
                const int lcb = (n * 16 + fr) * 2;
                *(f16*)(slice + lr * 128 + (lcb ^ ((lr & 7) << 4))) = (f16)(acc[m][n][j] + bsum);
            }
        }
    asm volatile("s_waitcnt lgkmcnt(0)" ::: "memory");   // wave-internal writes visible
    __builtin_amdgcn_sched_barrier(0);                    // rule 18: pin reads after wait

    // phase 2: packed coalesced stores (16B/lane, 8x128B segments/inst)
    f16* dst;
    int ld;
    if constexpr (EPI == 0)      { dst = (sel == 0) ? g_q : (sel == 1) ? g_k : g_v; ld = 1024; }
    else if constexpr (EPI == 1) { dst = g_sg;               ld = TT;   }
    else                         { dst = g_part[blockIdx.z]; ld = 1024; }

#pragma unroll
    for (int i = 0; i < 16; ++i) {
        const int r  = i * 8 + (l >> 3);
        const int cb = (l & 7) * 16;
        f16x8 vv = *(const f16x8*)(slice + r * 128 + (cb ^ ((r & 7) << 4)));
        *(f16x8*)&dst[(size_t)(crow0 + r) * ld + cb0 + (l & 7) * 8] = vv;
    }
}

// sum 4 split-K f16 partials -> g_ret f16
__global__ __launch_bounds__(256) void reduce_parts() {
    size_t i = (size_t)(blockIdx.x * 256 + threadIdx.x) * 8;
    f16x8 a = *(const f16x8*)&g_part[0][i];
    f16x8 b = *(const f16x8*)&g_part[1][i];
    f16x8 cc = *(const f16x8*)&g_part[2][i];
    f16x8 d = *(const f16x8*)&g_part[3][i];
    f16x8 o;
#pragma unroll
    for (int j = 0; j < 8; ++j)
        o[j] = (f16)((float)a[j] + (float)b[j] + (float)cc[j] + (float)d[j]);
    *(f16x8*)&g_ret[i] = o;
}

// sum 4 split-K f16 partials + bias + PReLU -> out f32
__global__ __launch_bounds__(256) void reduce_out(const float* __restrict__ br,
                                                  const float* __restrict__ prelu_a,
                                                  float* __restrict__ out) {
    size_t i = (size_t)(blockIdx.x * 256 + threadIdx.x) * 8;
    f16x8 a = *(const f16x8*)&g_part[0][i];
    f16x8 b = *(const f16x8*)&g_part[1][i];
    f16x8 cc = *(const f16x8*)&g_part[2][i];
    f16x8 d = *(const f16x8*)&g_part[3][i];
    const float pa = *prelu_a;
    const int col = (int)(i & 1023);
    const f32x4 b0 = *(const f32x4*)&br[col];
    const f32x4 b1 = *(const f32x4*)&br[col + 4];
    f32x4 o0, o1;
#pragma unroll
    for (int j = 0; j < 4; ++j) {
        float s = (float)a[j] + (float)b[j] + (float)cc[j] + (float)d[j] + b0[j];
        o0[j] = (s >= 0.f) ? s : pa * s;
    }
#pragma unroll
    for (int j = 0; j < 4; ++j) {
        float s = (float)a[j + 4] + (float)b[j + 4] + (float)cc[j + 4] + (float)d[j + 4] + b1[j];
        o1[j] = (s >= 0.f) ? s : pa * s;
    }
    *(f32x4*)&out[i] = o0;
    *(f32x4*)&out[i + 4] = o1;
}

extern "C" void kernel_launch(void* const* d_in, const int* in_sizes, int n_in,
                              void* d_out, int out_size, void* d_ws, size_t ws_size,
                              hipStream_t stream) {
    const float* x     = (const float*)d_in[0];
    const float* gamma = (const float*)d_in[1];
    const float* Wq    = (const float*)d_in[2];
    const float* bq    = (const float*)d_in[3];
    const float* Wk    = (const float*)d_in[4];
    const float* bk    = (const float*)d_in[5];
    const float* Wv    = (const float*)d_in[6];
    const float* bv    = (const float*)d_in[7];
    const float* Wr    = (const float*)d_in[8];
    const float* br    = (const float*)d_in[9];
    const float* pa    = (const float*)d_in[10];
    float* out = (float*)d_out;

    prep_cast_x<<<TT * DIN / 8 / 256, 256, 0, stream>>>(x);
    prep_transpose<<<dim3(DIN * DIN / 256, 4), 256, 0, stream>>>(Wq, Wk, Wv, Wr);

    // EPI 0: qkv  M=4096 N=3072  (192 blocks)
    gemm8<0><<<dim3(12, 16), 512, 0, stream>>>(bq, bk, bv);
    transpose_v<<<dim3(16, 64), 256, 0, stream>>>();
    // EPI 1: S = q k^T  M=4096 N=4096  (256 blocks)
    gemm8<1><<<dim3(16, 16), 512, 0, stream>>>(bq, bk, bv);
    // streaming gamma multiply (in-place on g_sg)
    gamma_mult<<<2048, 256, 0, stream>>>(gamma);
    // EPI 2: retained partials, split-K=4 over K=4096  (256 blocks)
    gemm8<2><<<dim3(4, 16, 4), 512, 0, stream>>>(bq, bk, bv);
    reduce_parts<<<TT * DIN / 8 / 256, 256, 0, stream>>>();
    // EPI 3: out partials, split-K=4 over K=1024 (NT=4)  (256 blocks)
    gemm8<3><<<dim3(4, 16, 4), 512, 0, stream>>>(bq, bk, bv);
    reduce_out<<<TT * DIN / 8 / 256, 256, 0, stream>>>(br, pa, out);
}

// Round 8
// 177.249 us; speedup vs baseline: 1.3230x; 1.1311x over previous
//
#include <hip/hip_runtime.h>

#define TT 4096
#define DIN 1024

typedef _Float16 f16;
typedef __attribute__((ext_vector_type(8))) _Float16 f16x8;
typedef __attribute__((ext_vector_type(4))) _Float16 f16x4;
typedef __attribute__((ext_vector_type(4))) float f32x4;

// ---- device-global scratch ----
__device__ f16 g_xh[TT * DIN];               // x cast to f16            8 MB
__device__ f16 g_wqkvT[3 * DIN * DIN];       // [Wq^T|Wk^T|Wv^T] f16     6 MB
__device__ f16 g_wrT[DIN * DIN];             // Wr^T f16                 2 MB
__device__ f16 g_q[TT * DIN];                // q                        8 MB
__device__ f16 g_k[TT * DIN];                // k                        8 MB
__device__ f16 g_v[TT * DIN];                // v row-major              8 MB
__device__ f16 g_vT[DIN * TT];               // v transposed             8 MB
__device__ f16 g_sg[(size_t)TT * TT];        // gamma .* (q k^T)        32 MB
__device__ f16 g_part[4][TT * DIN];          // split-K partials f16    32 MB
__device__ f16 g_ret[TT * DIN];              // retained                 8 MB

// ---- prep kernels ----
__global__ __launch_bounds__(256) void prep_cast_x(const float* __restrict__ x) {
    int i = (blockIdx.x * 256 + threadIdx.x) * 8;
    f32x4 a = *(const f32x4*)&x[i];
    f32x4 b = *(const f32x4*)&x[i + 4];
    f16x8 o;
#pragma unroll
    for (int j = 0; j < 4; ++j) { o[j] = (f16)a[j]; o[j + 4] = (f16)b[j]; }
    *(f16x8*)&g_xh[i] = o;
}

// LDS-tiled transpose-cast: dst[j][k] = (f16)src[k][j], 64x64 f32 tiles.
// Old version read lane-stride-4KB (16x fetch amplification); this one is
// coalesced on both sides (64B segments in, 128B row segments out).
__global__ __launch_bounds__(256) void prep_transpose(const float* __restrict__ Wq,
                                                      const float* __restrict__ Wk,
                                                      const float* __restrict__ Wv,
                                                      const float* __restrict__ Wr) {
    __shared__ float tt[64][68];                     // 272B rows: 16B-aligned
    const int which = blockIdx.z;
    const float* src = (which == 0) ? Wq : (which == 1) ? Wk : (which == 2) ? Wv : Wr;
    f16* dst = (which < 3) ? (g_wqkvT + (size_t)which * DIN * DIN) : g_wrT;
    const int t = threadIdx.x;
    const int r = t >> 2;                            // 0..63
    const int c0 = (t & 3) * 4;
#pragma unroll
    for (int ch = 0; ch < 4; ++ch)
        *(f32x4*)&tt[r][c0 + ch * 16] =
            *(const f32x4*)&src[(size_t)(blockIdx.y * 64 + r) * DIN + blockIdx.x * 64 + c0 + ch * 16];
    __syncthreads();
#pragma unroll
    for (int p = 0; p < 2; ++p) {
        const int j  = (t >> 3) + p * 32;            // dst row (= src col)
        const int k0 = (t & 7) * 8;
        f16x8 o;
#pragma unroll
        for (int jj = 0; jj < 8; ++jj) o[jj] = (f16)tt[k0 + jj][j];
        *(f16x8*)&dst[(size_t)(blockIdx.x * 64 + j) * DIN + blockIdx.y * 64 + k0] = o;
    }
}

// LDS-tiled transpose: g_v [4096][1024] -> g_vT [1024][4096]
__global__ __launch_bounds__(256) void transpose_v() {
    __shared__ f16 t[64][72];
    const int bc = blockIdx.x;
    const int br = blockIdx.y;
    const int tdx = threadIdx.x;
    const int r0 = tdx >> 3;
    const int c8 = (tdx & 7) * 8;
#pragma unroll
    for (int p = 0; p < 2; ++p) {
        int r = r0 + p * 32;
        *(f16x8*)&t[r][c8] = *(const f16x8*)&g_v[(size_t)(br * 64 + r) * DIN + bc * 64 + c8];
    }
    __syncthreads();
#pragma unroll
    for (int p = 0; p < 2; ++p) {
        int c = r0 + p * 32;
        f16x8 v;
#pragma unroll
        for (int j = 0; j < 8; ++j) v[j] = t[c8 + j][c];
        *(f16x8*)&g_vT[(size_t)(bc * 64 + c) * TT + br * 64 + c8] = v;
    }
}

// ---- async global->LDS, 16B per lane, wave-uniform LDS base ----
__device__ __forceinline__ void gload_lds16(const void* g, void* l) {
    __builtin_amdgcn_global_load_lds(
        (const __attribute__((address_space(1))) unsigned int*)g,
        (__attribute__((address_space(3))) unsigned int*)l,
        16, 0, 0);
}

// ================= 256x256 8-phase GEMM, C = A * B^T =================
// BK=64, 8 waves (2Mx4N), per-wave 128x64 out. LDS: 2 tile-buffers x 64KB.
// Swizzle: byte ^= (row&7)<<4 on stage SOURCE col and ds_read col.
// vmcnt ledger: steady kt outstanding = B(kt)4 + A(kt)4 + B(kt+1)4 = 12 ->
// vmcnt(4). Last kt: full drain vmcnt(0) (race fix, r3).
//
// Epilogue: per-wave LDS micro-repack -> packed f16x8 stores (r7, validated).
// EPI 0: -> q|k|v f16 (+bias), select by bx>>2
// EPI 1: -> g_sg = gamma .* S ; gamma fused in store phase: full-line f32x4
//         pair loads batched 8-iters deep (latency-hidden), then mul+store.
// EPI 2: -> g_part[z] f16, split-K over blockIdx.z (K=4096/4)
// EPI 3: -> g_part[z] f16, split-K over blockIdx.z (K=1024/4, NT=4)
template <int EPI>
__global__ __launch_bounds__(512, 2) void gemm8(const float* __restrict__ gamma,
                                                const float* __restrict__ bq,
                                                const float* __restrict__ bk,
                                                const float* __restrict__ bv) {
    constexpr int NT  = (EPI == 3) ? 4 : 16;         // K-tiles of 64
    constexpr int ld2A = (EPI == 2) ? 8192 : 2048;   // A row bytes
    constexpr int ld2B = (EPI == 2) ? 8192 : 2048;   // B row bytes

    const f16* Ap = (EPI == 0) ? g_xh : (EPI == 1) ? g_q : (EPI == 2) ? g_sg : g_ret;
    const f16* Bp = (EPI == 0) ? g_wqkvT : (EPI == 1) ? g_k : (EPI == 2) ? g_vT : g_wrT;
    const int kb_base = (EPI == 2) ? blockIdx.z * 2048
                      : (EPI == 3) ? blockIdx.z * 512 : 0;   // byte offset of K-slice

    __shared__ __align__(16) char smem[131072];

    const int t = threadIdx.x;
    const int w = t >> 6, l = t & 63;
    const int wr = w >> 2, wc = w & 3;               // 2M x 4N waves
    const int fr = l & 15;
    const int fkb = (l >> 4) * 16;                   // fragment k-byte (0..48)

    // XCD swizzle over (x,y) (bijective: all grids have nwg%8==0)
    const int nx = gridDim.x;
    const int lin = blockIdx.y * nx + blockIdx.x;
    const int cpx = (nx * gridDim.y) >> 3;
    const int sw = (lin & 7) * cpx + (lin >> 3);
    const int bx = sw % nx, by = sw / nx;
    const int arow0 = by * 256;
    const int bcol0 = bx * 256;

    auto stage = [&](const f16* M, int ld2, int row0, int kb0, int dstoff) {
#pragma unroll
        for (int r = 0; r < 2; ++r) {
            int off = r * 8192 + w * 1024;           // wave-uniform LDS offset
            int row = (off + l * 16) >> 7;
            int cb  = (l & 7) * 16;
            int scb = cb ^ ((row & 7) << 4);         // inverse-swizzle the SOURCE
            const char* src = (const char*)M + (size_t)(row0 + row) * ld2 + kb0 + scb;
            gload_lds16(src, smem + dstoff + off);
        }
    };

    auto ldsA = [&](int c, int m, int ks) -> f16x8 {
        int lr = m * 16 + fr;
        int kb = ks * 64 + fkb;
        return *(const f16x8*)(smem + c * 65536 + wr * 16384 + lr * 128 + (kb ^ ((lr & 7) << 4)));
    };
    auto ldsB = [&](int c, int n, int ks) -> f16x8 {
        int lc = (wc & 1) * 64 + n * 16 + fr;
        int kb = ks * 64 + fkb;
        return *(const f16x8*)(smem + c * 65536 + 32768 + (wc >> 1) * 16384 + lc * 128 + (kb ^ ((lc & 7) << 4)));
    };

#define KB(kt) (kb_base + (kt) * 128)

    // prologue: tile0 complete + tile1 B-halves (12 loads/thread in flight)
    stage(Ap, ld2A, arow0,       KB(0), 0);
    stage(Ap, ld2A, arow0 + 128, KB(0), 16384);
    stage(Bp, ld2B, bcol0,       KB(0), 32768);
    stage(Bp, ld2B, bcol0 + 128, KB(0), 49152);
    stage(Bp, ld2B, bcol0,       KB(1), 65536 + 32768);
    stage(Bp, ld2B, bcol0 + 128, KB(1), 65536 + 49152);

    f32x4 acc[8][4] = {};
    f16x8 bf[4][2];

#define GPHASE(MB, STAGE_STMT)                                              \
    {                                                                       \
        f16x8 af[2][2];                                                     \
        _Pragma("unroll") for (int i = 0; i < 2; ++i)                       \
            _Pragma("unroll") for (int ks = 0; ks < 2; ++ks)                \
                af[i][ks] = ldsA(c, (MB) + i, ks);                          \
        STAGE_STMT;                                                         \
        __builtin_amdgcn_s_barrier();                                       \
        __builtin_amdgcn_s_setprio(1);                                      \
        _Pragma("unroll") for (int i = 0; i < 2; ++i)                       \
            _Pragma("unroll") for (int n = 0; n < 4; ++n)                   \
                _Pragma("unroll") for (int ks = 0; ks < 2; ++ks)            \
                    acc[(MB) + i][n] = __builtin_amdgcn_mfma_f32_16x16x32_f16( \
                        af[i][ks], bf[n][ks], acc[(MB) + i][n], 0, 0, 0);   \
        __builtin_amdgcn_s_setprio(0);                                      \
        __builtin_amdgcn_s_barrier();                                       \
    }

    for (int kt = 0; kt < NT; ++kt) {
        const int c = kt & 1;
        if (kt == NT - 1) asm volatile("s_waitcnt vmcnt(0)" ::: "memory");
        else              asm volatile("s_waitcnt vmcnt(4)" ::: "memory");
        __builtin_amdgcn_s_barrier();
#pragma unroll
        for (int n = 0; n < 4; ++n)
#pragma unroll
            for (int ks = 0; ks < 2; ++ks) bf[n][ks] = ldsB(c, n, ks);
        GPHASE(0, if (kt + 1 < NT) stage(Ap, ld2A, arow0,       KB(kt + 1), (c ^ 1) * 65536))
        GPHASE(2, if (kt + 1 < NT) stage(Ap, ld2A, arow0 + 128, KB(kt + 1), (c ^ 1) * 65536 + 16384))
        GPHASE(4, if (kt + 2 < NT) stage(Bp, ld2B, bcol0,       KB(kt + 2), c * 65536 + 32768))
        GPHASE(6, if (kt + 2 < NT) stage(Bp, ld2B, bcol0 + 128, KB(kt + 2), c * 65536 + 49152))
    }
#undef GPHASE
#undef KB

    // ------------- per-wave LDS micro-repack epilogue -------------
    __syncthreads();                                 // K-loop LDS fully retired
    char* slice = smem + w * 16384;                  // wave-private f16[128][64]
    const int rb = (l >> 4) * 4;
    const int crow0 = arow0 + wr * 128;
    const int ccol0 = bcol0 + wc * 64;

    const int sel = (EPI == 0) ? (bx >> 2) : 0;      // 0=q 1=k 2=v
    const float* bias0 = (EPI == 0) ? ((sel == 0) ? bq : (sel == 1) ? bk : bv) : nullptr;
    const int cb0 = (EPI == 0) ? (ccol0 - sel * 1024) : ccol0;

    // phase 1: acc (+bias) -> f16 into swizzled wave slice
#pragma unroll
    for (int m = 0; m < 8; ++m)
#pragma unroll
        for (int n = 0; n < 4; ++n) {
            float bsum = 0.f;
            if constexpr (EPI == 0) bsum = bias0[cb0 + n * 16 + fr];
#pragma unroll
            for (int j = 0; j < 4; ++j) {
                const int lr = m * 16 + rb + j;
                const int lcb = (n * 16 + fr) * 2;
                *(f16*)(slice + lr * 128 + (lcb ^ ((lr & 7) << 4))) = (f16)(acc[m][n][j] + bsum);
            }
        }
    asm volatile("s_waitcnt lgkmcnt(0)" ::: "memory");   // wave-internal writes visible
    __builtin_amdgcn_sched_barrier(0);                    // rule 18: pin reads after wait

    // phase 2: packed coalesced stores (16B/lane, 8x128B segments/inst)
    if constexpr (EPI == 1) {
        // gamma fused: two groups of 8 iters; batch-issue 16 f32x4 gamma loads
        // per group (latency-hidden), then ds_read + mul + packed store.
#pragma unroll 1
        for (int g = 0; g < 2; ++g) {
            f32x4 ga[8][2];
#pragma unroll
            for (int i = 0; i < 8; ++i) {
                const int r = (g * 8 + i) * 8 + (l >> 3);
                const float* gp = &gamma[(size_t)(crow0 + r) * TT + ccol0 + (l & 7) * 8];
                ga[i][0] = *(const f32x4*)gp;
                ga[i][1] = *(const f32x4*)(gp + 4);
            }
#pragma unroll
            for (int i = 0; i < 8; ++i) {
                const int r  = (g * 8 + i) * 8 + (l >> 3);
                const int cb = (l & 7) * 16;
                f16x8 vv = *(const f16x8*)(slice + r * 128 + (cb ^ ((r & 7) << 4)));
                f16x8 o;
#pragma unroll
                for (int j = 0; j < 4; ++j) {
                    o[j]     = (f16)((float)vv[j] * ga[i][0][j]);
                    o[j + 4] = (f16)((float)vv[j + 4] * ga[i][1][j]);
                }
                *(f16x8*)&g_sg[(size_t)(crow0 + r) * TT + ccol0 + (l & 7) * 8] = o;
            }
        }
    } else {
        f16* dst;
        int ld;
        if constexpr (EPI == 0) { dst = (sel == 0) ? g_q : (sel == 1) ? g_k : g_v; ld = 1024; }
        else                    { dst = g_part[blockIdx.z]; ld = 1024; }
#pragma unroll
        for (int i = 0; i < 16; ++i) {
            const int r  = i * 8 + (l >> 3);
            const int cb = (l & 7) * 16;
            f16x8 vv = *(const f16x8*)(slice + r * 128 + (cb ^ ((r & 7) << 4)));
            *(f16x8*)&dst[(size_t)(crow0 + r) * ld + cb0 + (l & 7) * 8] = vv;
        }
    }
}

// sum 4 split-K f16 partials -> g_ret f16
__global__ __launch_bounds__(256) void reduce_parts() {
    size_t i = (size_t)(blockIdx.x * 256 + threadIdx.x) * 8;
    f16x8 a = *(const f16x8*)&g_part[0][i];
    f16x8 b = *(const f16x8*)&g_part[1][i];
    f16x8 cc = *(const f16x8*)&g_part[2][i];
    f16x8 d = *(const f16x8*)&g_part[3][i];
    f16x8 o;
#pragma unroll
    for (int j = 0; j < 8; ++j)
        o[j] = (f16)((float)a[j] + (float)b[j] + (float)cc[j] + (float)d[j]);
    *(f16x8*)&g_ret[i] = o;
}

// sum 4 split-K f16 partials + bias + PReLU -> out f32
__global__ __launch_bounds__(256) void reduce_out(const float* __restrict__ br,
                                                  const float* __restrict__ prelu_a,
                                                  float* __restrict__ out) {
    size_t i = (size_t)(blockIdx.x * 256 + threadIdx.x) * 8;
    f16x8 a = *(const f16x8*)&g_part[0][i];
    f16x8 b = *(const f16x8*)&g_part[1][i];
    f16x8 cc = *(const f16x8*)&g_part[2][i];
    f16x8 d = *(const f16x8*)&g_part[3][i];
    const float pa = *prelu_a;
    const int col = (int)(i & 1023);
    const f32x4 b0 = *(const f32x4*)&br[col];
    const f32x4 b1 = *(const f32x4*)&br[col + 4];
    f32x4 o0, o1;
#pragma unroll
    for (int j = 0; j < 4; ++j) {
        float s = (float)a[j] + (float)b[j] + (float)cc[j] + (float)d[j] + b0[j];
        o0[j] = (s >= 0.f) ? s : pa * s;
    }
#pragma unroll
    for (int j = 0; j < 4; ++j) {
        float s = (float)a[j + 4] + (float)b[j + 4] + (float)cc[j + 4] + (float)d[j + 4] + b1[j];
        o1[j] = (s >= 0.f) ? s : pa * s;
    }
    *(f32x4*)&out[i] = o0;
    *(f32x4*)&out[i + 4] = o1;
}

extern "C" void kernel_launch(void* const* d_in, const int* in_sizes, int n_in,
                              void* d_out, int out_size, void* d_ws, size_t ws_size,
                              hipStream_t stream) {
    const float* x     = (const float*)d_in[0];
    const float* gamma = (const float*)d_in[1];
    const float* Wq    = (const float*)d_in[2];
    const float* bq    = (const float*)d_in[3];
    const float* Wk    = (const float*)d_in[4];
    const float* bk    = (const float*)d_in[5];
    const float* Wv    = (const float*)d_in[6];
    const float* bv    = (const float*)d_in[7];
    const float* Wr    = (const float*)d_in[8];
    const float* br    = (const float*)d_in[9];
    const float* pa    = (const float*)d_in[10];
    float* out = (float*)d_out;

    prep_cast_x<<<TT * DIN / 8 / 256, 256, 0, stream>>>(x);
    prep_transpose<<<dim3(16, 16, 4), 256, 0, stream>>>(Wq, Wk, Wv, Wr);

    // EPI 0: qkv  M=4096 N=3072  (192 blocks)
    gemm8<0><<<dim3(12, 16), 512, 0, stream>>>(gamma, bq, bk, bv);
    transpose_v<<<dim3(16, 64), 256, 0, stream>>>();
    // EPI 1: g_sg = gamma .* (q k^T)  M=4096 N=4096  (256 blocks)
    gemm8<1><<<dim3(16, 16), 512, 0, stream>>>(gamma, bq, bk, bv);
    // EPI 2: retained partials, split-K=4 over K=4096  (256 blocks)
    gemm8<2><<<dim3(4, 16, 4), 512, 0, stream>>>(gamma, bq, bk, bv);
    reduce_parts<<<TT * DIN / 8 / 256, 256, 0, stream>>>();
    // EPI 3: out partials, split-K=4 over K=1024 (NT=4)  (256 blocks)
    gemm8<3><<<dim3(4, 16, 4), 512, 0, stream>>>(gamma, bq, bk, bv);
    reduce_out<<<TT * DIN / 8 / 256, 256, 0, stream>>>(br, pa, out);
}